// Round 1
// baseline (150.003 us; speedup 1.0000x reference)
//
#include <hip/hip_runtime.h>

// Fused loss: 0.2 * mean(dx^2 - dy^2) + 0.8 * masked-MSE(target>0)
// dx = Sv(vert) ∘ D(horiz) on e = pred - target;  dy = D(vert) ∘ Sv(horiz)
//   Sv = [0.25, 1, 1.5, 1, 0.25], D = [-0.25, -0.5, 0, 0.5, 0.25]
// reflect-101 halo of 2 on e (exact; absmax 0.0 in R1-R6).
//
// R7: e-staging restructure. R6 was latency-bound (VALUBusy 31%, HBM 22%,
// occupancy 16.5% with 76 KB LDS -> 2 blocks/CU). Phase B only consumes
// e = pred - target; raw target is only needed for the masked MSE. So:
// reg-stage both tensors, fold masked-MSE into the staging pass, write ONLY
// e to LDS. LDS 76->38 KB => 4 blocks/CU (16 waves), phase-B LDS reads
// halved (3 ds_read_b128/hpass), inner loop loses the 8 subs + mse ops.
// Reduction via private workspace slots + loss_final (R6's verified scheme).

#define TW 256
#define TH 32
#define LROWS 36   // TH + 4
#define LW 264     // row stride (words): interior cols 4..259, halo 2,3,260,261

__device__ __forceinline__ int reflect101(int i, int n) {
    if (i < 0) i = -i;
    if (i >= n) i = 2 * n - 2 - i;
    return i;
}

__global__ __launch_bounds__(256) void loss_main(
    const float* __restrict__ pred, const float* __restrict__ target,
    double* __restrict__ part, int H, int W)
{
    __shared__ float esh[LROWS][LW];
    __shared__ float partials[4][3];

    const int tid  = threadIdx.x;
    const int lane = tid & 63;
    const int w    = tid >> 6;
    const int r0 = blockIdx.y * TH;
    const int c0 = blockIdx.x * TW;

    float mse = 0.f, cnt = 0.f, g = 0.f;

    // ---- halo columns: 144 threads, 1 (row, halo-col) pair each.
    // Issue these strided (cache-line-each) loads FIRST so their latency
    // overlaps the coalesced interior staging below.
    float hp = 0.f, ht = 0.f;
    int hrow = 0, hlc = 0;
    const bool hasHalo = (tid < 144);
    if (hasHalo) {
        hrow = tid >> 2;
        const int hc = tid & 3;
        hlc = (hc < 2) ? (2 + hc) : (258 + hc);   // 2,3,260,261
        const int gc = reflect101((hc < 2) ? (c0 - 2 + hc)
                                           : (c0 + 254 + hc), W);
        const int gr = reflect101(r0 - 2 + hrow, H);
        const size_t off = (size_t)gr * W + gc;
        hp = pred[off];
        ht = target[off];
    }

    // ---- interior staging: 9 float4 row-segments per thread, both tensors.
    // row = j*4 + w (0..35), cols c0 + 4*lane .. +3. All 18 loads issued
    // before use for MLP; e written to LDS; masked MSE folded in for the
    // 32 interior rows (staged rows 2..33 == global rows r0..r0+31).
    float4 pv[9], tv[9];
#pragma unroll
    for (int j = 0; j < 9; ++j) {
        const int row = j * 4 + w;
        const int gr  = reflect101(r0 - 2 + row, H);
        const size_t off = (size_t)gr * W + c0 + lane * 4;
        pv[j] = *(const float4*)(pred   + off);
        tv[j] = *(const float4*)(target + off);
    }
#pragma unroll
    for (int j = 0; j < 9; ++j) {
        const int row = j * 4 + w;
        float4 e;
        e.x = pv[j].x - tv[j].x;
        e.y = pv[j].y - tv[j].y;
        e.z = pv[j].z - tv[j].z;
        e.w = pv[j].w - tv[j].w;
        *(float4*)&esh[row][4 + 4 * lane] = e;
        if (row >= 2 && row < 34) {           // wave-uniform predicate
            if (tv[j].x > 0.f) { mse += e.x * e.x; cnt += 1.f; }
            if (tv[j].y > 0.f) { mse += e.y * e.y; cnt += 1.f; }
            if (tv[j].z > 0.f) { mse += e.z * e.z; cnt += 1.f; }
            if (tv[j].w > 0.f) { mse += e.w * e.w; cnt += 1.f; }
        }
    }
    if (hasHalo) esh[hrow][hlc] = hp - ht;

    __syncthreads();

    // ---- phase B: separable conv on e, rolling 5-row window ----
    const int cg = lane;            // output LDS cols 4+4cg .. 7+4cg
    const int rb = w * 8;           // window rows rb .. rb+11

    float4 D0, D1, D2, D3, D4, S0, S1, S2, S3, S4;

    auto hpass = [&](int rw, float4& D_, float4& S_) {
        const float4 a = *(const float4*)&esh[rw][4 * cg];
        const float4 b = *(const float4*)&esh[rw][4 * cg + 4];
        const float4 c = *(const float4*)&esh[rw][4 * cg + 8];
        D_.x = 0.25f * (b.z - a.z) + 0.5f * (b.y - a.w);
        D_.y = 0.25f * (b.w - a.w) + 0.5f * (b.z - b.x);
        D_.z = 0.25f * (c.x - b.x) + 0.5f * (b.w - b.y);
        D_.w = 0.25f * (c.y - b.y) + 0.5f * (c.x - b.z);
        S_.x = 0.25f * (a.z + b.z) + (a.w + b.y) + 1.5f * b.x;
        S_.y = 0.25f * (a.w + b.w) + (b.x + b.z) + 1.5f * b.y;
        S_.z = 0.25f * (b.x + c.x) + (b.y + b.w) + 1.5f * b.z;
        S_.w = 0.25f * (b.y + c.y) + (b.z + c.x) + 1.5f * b.w;
    };

    hpass(rb + 0, D0, S0);
    hpass(rb + 1, D1, S1);
    hpass(rb + 2, D2, S2);
    hpass(rb + 3, D3, S3);

#pragma unroll
    for (int k = 0; k < 8; ++k) {
        hpass(rb + 4 + k, D4, S4);
        const float dx0 = 0.25f * (D0.x + D4.x) + (D1.x + D3.x) + 1.5f * D2.x;
        const float dx1 = 0.25f * (D0.y + D4.y) + (D1.y + D3.y) + 1.5f * D2.y;
        const float dx2 = 0.25f * (D0.z + D4.z) + (D1.z + D3.z) + 1.5f * D2.z;
        const float dx3 = 0.25f * (D0.w + D4.w) + (D1.w + D3.w) + 1.5f * D2.w;
        const float dy0 = 0.25f * (S4.x - S0.x) + 0.5f * (S3.x - S1.x);
        const float dy1 = 0.25f * (S4.y - S0.y) + 0.5f * (S3.y - S1.y);
        const float dy2 = 0.25f * (S4.z - S0.z) + 0.5f * (S3.z - S1.z);
        const float dy3 = 0.25f * (S4.w - S0.w) + 0.5f * (S3.w - S1.w);
        g += (dx0 * dx0 - dy0 * dy0) + (dx1 * dx1 - dy1 * dy1)
           + (dx2 * dx2 - dy2 * dy2) + (dx3 * dx3 - dy3 * dy3);
        D0 = D1; D1 = D2; D2 = D3; D3 = D4;
        S0 = S1; S1 = S2; S2 = S3; S3 = S4;
    }

    // ---- reduction: wave shuffle -> LDS partials -> PLAIN STORES (no atomics)
    for (int off = 32; off > 0; off >>= 1) {
        mse += __shfl_down(mse, off, 64);
        cnt += __shfl_down(cnt, off, 64);
        g   += __shfl_down(g,   off, 64);
    }
    if (lane == 0) {
        partials[w][0] = mse;
        partials[w][1] = cnt;
        partials[w][2] = g;
    }
    __syncthreads();
    if (tid == 0) {
        float m = 0.f, c2 = 0.f, gg = 0.f;
        for (int wv = 0; wv < 4; ++wv) {
            m  += partials[wv][0];
            c2 += partials[wv][1];
            gg += partials[wv][2];
        }
        const int bid = blockIdx.y * gridDim.x + blockIdx.x;
        double* slot = part + 3 * bid;
        slot[0] = (double)m;
        slot[1] = (double)c2;
        slot[2] = (double)gg;
    }
}

__global__ __launch_bounds__(256) void loss_final(
    const double* __restrict__ part, int nslots,
    float* __restrict__ out, double inv_hw)
{
    __shared__ double red[4][3];
    double m = 0.0, c = 0.0, g = 0.0;
    for (int s = threadIdx.x; s < nslots; s += 256) {
        m += part[3 * s];
        c += part[3 * s + 1];
        g += part[3 * s + 2];
    }
    for (int off = 32; off > 0; off >>= 1) {
        m += __shfl_down(m, off, 64);
        c += __shfl_down(c, off, 64);
        g += __shfl_down(g, off, 64);
    }
    const int w = threadIdx.x >> 6;
    if ((threadIdx.x & 63) == 0) { red[w][0] = m; red[w][1] = c; red[w][2] = g; }
    __syncthreads();
    if (threadIdx.x == 0) {
        m = red[0][0] + red[1][0] + red[2][0] + red[3][0];
        c = red[0][1] + red[1][1] + red[2][1] + red[3][1];
        g = red[0][2] + red[1][2] + red[2][2] + red[3][2];
        const double cnt = c < 1.0 ? 1.0 : c;
        out[0] = (float)(0.2 * (g * inv_hw) + 0.8 * (m / cnt));
    }
}

extern "C" void kernel_launch(void* const* d_in, const int* in_sizes, int n_in,
                              void* d_out, int out_size, void* d_ws, size_t ws_size,
                              hipStream_t stream) {
    const float* pred   = (const float*)d_in[0];
    const float* target = (const float*)d_in[1];
    float* out   = (float*)d_out;
    double* part = (double*)d_ws;

    const int H = 4096, W = 4096;
    const int nblocks = (W / TW) * (H / TH);   // 2048; 48 KB of ws

    dim3 grid(W / TW, H / TH);   // (16, 128) = 2048 blocks
    loss_main<<<grid, 256, 0, stream>>>(pred, target, part, H, W);
    loss_final<<<1, 256, 0, stream>>>(part, nblocks, out,
                                      1.0 / ((double)H * (double)W));
}